// Round 2
// baseline (139.098 us; speedup 1.0000x reference)
//
#include <hip/hip_runtime.h>
#include <hip/hip_bf16.h>

// Flash-attention fwd, block-causal packed docs. fp32 HBM, bf16 MFMA.
// B=1, H=8, D=128. 4 waves/block, BR=64, BC=64, grid 512, 2 blocks/CU.
// R11: two-kernel scheme.
//  1) prepack: one-shot fp32->bf16 conversion into d_ws:
//     wsK  [H*S][128] bf16, 16B chunks XOR-permuted by (row&7)<<4
//     wsVT [H][S/64 tiles][128 d][64 keys] bf16, R10 key-permuted PV layout
//     (dword c=16ks+4q+w: w0=keys 32ks+4q+{0,1}, w1={2,3}, w2=+16+{0,1},
//      w3=+16+{2,3}), same XOR permute by (d&7)<<4. Tile = 16KB contiguous.
//  2) fa_fwd: staging = 8x global_load_lds dwordx4 per thread, direct to
//     LINEAR LDS (rule 21: linear dest + pre-swizzled source + swizzled
//     ds_read, same involution). No register round-trip, no cvt_pk, no
//     ds_write on the per-tile chain; 32KB/tile bf16 vs 64KB fp32.
//     Bank classes on ds_read_b128: 4*(quad^(l16&7)) -> 8 uniform classes,
//     same distribution the old KSTR=136/VSTR=33 padding achieved.
// Keeps R10: swapped-operand QK^T (lane owns one query), P-in-registers PV,
// in-lane softmax + 2 shfl, (16,1) balanced pairing (right for a
// latency-bound chain: the 16-tile block runs nearly solo), setprio around
// MFMA clusters. LDS 71680 -> 65536 B.

#define HD 128
#define BR 64
#define BC 64

typedef __attribute__((ext_vector_type(8))) short short8;
typedef __attribute__((ext_vector_type(4))) float floatx4;

__device__ inline unsigned packbf2(float lo, float hi) {
    __hip_bfloat162 h2 = __float22bfloat162_rn(make_float2(lo, hi));
    return *reinterpret_cast<unsigned*>(&h2);   // low16 = lo, high16 = hi
}
__device__ inline short bfs(float f) {
    __hip_bfloat16 b = __float2bfloat16(f);
    return *reinterpret_cast<short*>(&b);
}

__device__ inline void gll16(const void* g, void* l) {
    __builtin_amdgcn_global_load_lds(
        (const __attribute__((address_space(1))) unsigned int*)g,
        (__attribute__((address_space(3))) unsigned int*)l, 16, 0, 0);
}

// ---------------- prepack: fp32 -> bf16, swizzled ----------------
__global__ __launch_bounds__(256) void prepack(
    const float* __restrict__ K, const float* __restrict__ V,
    unsigned short* __restrict__ wsK, unsigned short* __restrict__ wsVT,
    int S)
{
    const int tid = threadIdx.x;
    const int nKblk = (8 * S * 16) / 256;     // K chunks / 256
    const int bid = blockIdx.x;
    if (bid < nKblk) {
        // K: one 16B output chunk (8 bf16 = 8 fp32 in) per thread, coalesced.
        const int cid = bid * 256 + tid;
        const int row = cid >> 4;              // global row (h*S + r)
        const int c   = cid & 15;
        const float* src = K + (size_t)row * HD + c * 8;
        float4 f0 = *(const float4*)src;
        float4 f1 = *(const float4*)(src + 4);
        union { uint4 q; unsigned u[4]; } w;
        w.u[0] = packbf2(f0.x, f0.y); w.u[1] = packbf2(f0.z, f0.w);
        w.u[2] = packbf2(f1.x, f1.y); w.u[3] = packbf2(f1.z, f1.w);
        *(uint4*)((char*)wsK + (size_t)row * 256 + ((c * 16) ^ ((row & 7) << 4))) = w.q;
    } else {
        // V^T: block = one (h, tile); thread = (d, jj), 4 chunks each.
        const int ntile = S >> 6;
        const int b = bid - nKblk;
        const int h = b / ntile;
        const int t = b - h * ntile;
        const int d  = tid & 127;
        const int jj = tid >> 7;
        const float* vb = V + ((size_t)h * S + t * 64) * HD + d;
        char* dstrow = (char*)wsVT + ((size_t)(h * ntile + t) * HD + d) * 128;
        const int dx = (d & 7) << 4;
        #pragma unroll
        for (int u = 0; u < 4; ++u) {
            const int j  = jj * 4 + u;                     // chunk 0..7
            const int k0 = (j >> 2) * 32 + (j & 3) * 4;    // ks*32 + q*4
            float v0 = vb[(size_t)(k0 +  0) * HD];
            float v1 = vb[(size_t)(k0 +  1) * HD];
            float v2 = vb[(size_t)(k0 +  2) * HD];
            float v3 = vb[(size_t)(k0 +  3) * HD];
            float v4 = vb[(size_t)(k0 + 16) * HD];
            float v5 = vb[(size_t)(k0 + 17) * HD];
            float v6 = vb[(size_t)(k0 + 18) * HD];
            float v7 = vb[(size_t)(k0 + 19) * HD];
            union { uint4 q; unsigned u4[4]; } w;
            w.u4[0] = packbf2(v0, v1); w.u4[1] = packbf2(v2, v3);
            w.u4[2] = packbf2(v4, v5); w.u4[3] = packbf2(v6, v7);
            *(uint4*)(dstrow + ((j * 16) ^ dx)) = w.q;
        }
    }
}

// ---------------- main attention kernel ----------------
__global__ __launch_bounds__(256, 2) void fa_fwd(
    const float* __restrict__ Q,
    const unsigned short* __restrict__ wsK,
    const unsigned short* __restrict__ wsVT,
    const int* __restrict__ cu_seqlens, int n_cu,
    float* __restrict__ O,
    int S)
{
    __shared__ alignas(16) __hip_bfloat16 sK[2][BC * HD];    // 2 x 16KB
    __shared__ alignas(16) unsigned int   sVT[2][HD * 32];   // 2 x 16KB

    const int tid  = threadIdx.x;
    const int wave = tid >> 6;
    const int lane = tid & 63;
    const int quad = lane >> 4;
    const int l16  = lane & 15;
    const int kx   = (l16 & 7) << 4;        // read-side XOR (matches prepack)

    const int nqb = S / BR;
    const int h   = blockIdx.x & 7;
    const int g   = (int)(blockIdx.x >> 3);   // 0..nqb-1
    int qb;
    if (nqb == 64) {
        // balanced pairing: (g, g+32) ntiles sum to 17
        if (g < 32) qb = (g >> 4) * 16 + (15 - (g & 15));        // docs 0,1 desc
        else        qb = 32 + (((g - 32) >> 4) * 16) + (g & 15); // docs 2,3 asc
    } else {
        qb = nqb - 1 - g;
    }
    const int q0    = qb * BR;
    const int qw    = q0 + wave * 16;
    const int qlane = qw + l16;     // the ONE query this lane owns

    // ---- block-uniform doc geometry (needed before first stage) ----
    int blk_ds = 0;
    for (int i = 0; i < n_cu; ++i) {
        int c = cu_seqlens[i];
        if (c <= q0) blk_ds = c;
    }
    const int k_begin = blk_ds & ~(BC - 1);
    const int ntiles  = (q0 + BR - 1 - k_begin) / BC + 1;

    // ---- staging: 8x global_load_lds dwordx4 per thread ----
    const char* gkb = (const char*)wsK + (size_t)h * S * 256;
    const char* gvb = (const char*)wsVT + (size_t)h * (S >> 6) * 16384;
    const int lo = lane * 16;
    auto stage = [&](int kt, int buf) {
        const char* gk = gkb + (size_t)kt * 256 + wave * 4096 + lo;
        const char* gv = gvb + (size_t)(kt >> 6) * 16384 + wave * 4096 + lo;
        char* lk = (char*)&sK[buf][0] + wave * 4096;   // wave-uniform base
        char* lv = (char*)&sVT[buf][0] + wave * 4096;
        #pragma unroll
        for (int c = 0; c < 4; ++c) gll16(gk + c * 1024, lk + c * 1024);
        #pragma unroll
        for (int c = 0; c < 4; ++c) gll16(gv + c * 1024, lv + c * 1024);
    };

    stage(k_begin, 0);   // issue ASAP; latency hides under Q prologue

    const size_t hoff = (size_t)h * S * HD;
    const float* Qh = Q + hoff;
    float*       Oh = O + hoff;

    // ---- per-lane doc start ----
    int ds_lane = 0;
    for (int i = 0; i < n_cu; ++i) {
        int c = cu_seqlens[i];
        if (c <= qlane) ds_lane = c;
    }

    // ---- Q fragments (B-operand: lane holds Q[qlane][ks*32+quad*8+j]) ----
    short8 aq[4];
    {
        const float* qp = Qh + (size_t)qlane * HD + quad * 8;
        #pragma unroll
        for (int ks = 0; ks < 4; ++ks) {
            float4 a0 = *(const float4*)(qp + ks * 32);
            float4 a1 = *(const float4*)(qp + ks * 32 + 4);
            short8 a;
            a[0] = bfs(a0.x); a[1] = bfs(a0.y); a[2] = bfs(a0.z); a[3] = bfs(a0.w);
            a[4] = bfs(a1.x); a[5] = bfs(a1.y); a[6] = bfs(a1.z); a[7] = bfs(a1.w);
            aq[ks] = a;
        }
    }

    // oacc[dt][r] = O[qlane][dt*16 + quad*4 + r]  (O^T layout)
    floatx4 oacc[8];
    #pragma unroll
    for (int dt = 0; dt < 8; ++dt) oacc[dt] = (floatx4){0.f, 0.f, 0.f, 0.f};
    float m_r = -1e30f, l_r = 0.f;

    const float sl = 0.08838834764831845f * 1.4426950408889634f;

    __syncthreads();    // drains stage(k_begin) vmcnt + all waves ready

    for (int it = 0; it < ntiles; ++it) {
        const int kt  = k_begin + it * BC;
        const int buf = it & 1;

        if (it + 1 < ntiles) stage(kt + BC, buf ^ 1);

        const char* kbase = (const char*)&sK[buf][0];
        const char* vbase = (const char*)&sVT[buf][0];

        // ---- S^T = K Q^T (skip fully-masked 16-key blocks) ----
        floatx4 sc[4];
        __builtin_amdgcn_s_setprio(1);
        #pragma unroll
        for (int ct = 0; ct < 4; ++ct) {
            if (kt + ct * 16 <= qw + 15) {       // wave-uniform
                floatx4 c = (floatx4){0.f, 0.f, 0.f, 0.f};
                #pragma unroll
                for (int ks = 0; ks < 4; ++ks) {
                    short8 a = *(const short8*)(kbase + (ct * 16 + l16) * 256
                                                + (((ks * 4 + quad) << 4) ^ kx));
                    c = __builtin_amdgcn_mfma_f32_16x16x32_bf16(a, aq[ks], c, 0, 0, 0);
                }
                sc[ct] = c;
            } else {
                sc[ct] = (floatx4){-1e30f, -1e30f, -1e30f, -1e30f};
            }
        }
        __builtin_amdgcn_s_setprio(0);

        // ---- mask + scale ----
        #pragma unroll
        for (int ct = 0; ct < 4; ++ct) {
            if (kt + ct * 16 <= qw + 15) {
                #pragma unroll
                for (int r = 0; r < 4; ++r) {
                    const int key = kt + ct * 16 + quad * 4 + r;
                    const bool valid = (key <= qlane) && (key >= ds_lane);
                    float s = sc[ct][r] * sl;
                    sc[ct][r] = valid ? s : -1e30f;
                }
            }
        }

        // ---- online softmax: in-lane tree + 2 shfl ----
        float mx0 = fmaxf(fmaxf(sc[0][0], sc[0][1]), fmaxf(sc[0][2], sc[0][3]));
        float mx1 = fmaxf(fmaxf(sc[1][0], sc[1][1]), fmaxf(sc[1][2], sc[1][3]));
        float mx2 = fmaxf(fmaxf(sc[2][0], sc[2][1]), fmaxf(sc[2][2], sc[2][3]));
        float mx3 = fmaxf(fmaxf(sc[3][0], sc[3][1]), fmaxf(sc[3][2], sc[3][3]));
        float mx  = fmaxf(fmaxf(mx0, mx1), fmaxf(mx2, mx3));
        mx = fmaxf(mx, __shfl_xor(mx, 16, 64));
        mx = fmaxf(mx, __shfl_xor(mx, 32, 64));

        const float mnew = fmaxf(m_r, mx);
        const float al   = exp2f(m_r - mnew);
        m_r = mnew;

        float s0 = 0.f, s1 = 0.f, s2 = 0.f, s3 = 0.f;
        #pragma unroll
        for (int ct = 0; ct < 4; ++ct) {
            float p0 = exp2f(sc[ct][0] - m_r);
            float p1 = exp2f(sc[ct][1] - m_r);
            float p2 = exp2f(sc[ct][2] - m_r);
            float p3 = exp2f(sc[ct][3] - m_r);
            sc[ct][0] = p0; sc[ct][1] = p1; sc[ct][2] = p2; sc[ct][3] = p3;
            s0 += p0; s1 += p1; s2 += p2; s3 += p3;
        }
        l_r = l_r * al + ((s0 + s1) + (s2 + s3));
        #pragma unroll
        for (int dt = 0; dt < 8; ++dt) {
            #pragma unroll
            for (int r = 0; r < 4; ++r)
                oacc[dt][r] *= al;
        }

        // ---- O^T += V^T P^T (P stays in registers) ----
        __builtin_amdgcn_s_setprio(1);
        #pragma unroll
        for (int ks = 0; ks < 2; ++ks) {
            if (kt + ks * 32 <= qw + 15) {       // wave-uniform
                union { unsigned u[4]; short8 s; } pu;   // B-frag = own p-values
                pu.u[0] = packbf2(sc[2*ks][0],   sc[2*ks][1]);
                pu.u[1] = packbf2(sc[2*ks][2],   sc[2*ks][3]);
                pu.u[2] = packbf2(sc[2*ks+1][0], sc[2*ks+1][1]);
                pu.u[3] = packbf2(sc[2*ks+1][2], sc[2*ks+1][3]);
                #pragma unroll
                for (int dt = 0; dt < 8; ++dt) {
                    union { uint4 q; short8 s; } cv;
                    cv.q = *(const uint4*)(vbase + (dt * 16 + l16) * 128
                                           + (((ks * 4 + quad) << 4) ^ kx));
                    oacc[dt] = __builtin_amdgcn_mfma_f32_16x16x32_bf16(cv.s, pu.s, oacc[dt], 0, 0, 0);
                }
            }
        }
        __builtin_amdgcn_s_setprio(0);

        __syncthreads();   // drains vmcnt (next-tile stage) + readers of buf
    }

    // ---- epilogue: reduce l over quads, float4 stores ----
    l_r += __shfl_xor(l_r, 16, 64);
    l_r += __shfl_xor(l_r, 32, 64);
    const float inv = 1.0f / l_r;
    float* op = Oh + (size_t)qlane * HD + quad * 4;
    #pragma unroll
    for (int dt = 0; dt < 8; ++dt) {
        float4 st;
        st.x = oacc[dt][0] * inv;
        st.y = oacc[dt][1] * inv;
        st.z = oacc[dt][2] * inv;
        st.w = oacc[dt][3] * inv;
        *(float4*)(op + dt * 16) = st;
    }
}

extern "C" void kernel_launch(void* const* d_in, const int* in_sizes, int n_in,
                              void* d_out, int out_size, void* d_ws, size_t ws_size,
                              hipStream_t stream) {
    const float* q = (const float*)d_in[0];
    const float* k = (const float*)d_in[1];
    const float* v = (const float*)d_in[2];
    const int* cu = (const int*)d_in[3];
    const int n_cu = in_sizes[3];
    const int H = 8;
    const int S = in_sizes[0] / (H * HD);   // B=1
    float* out = (float*)d_out;

    unsigned short* wsK  = (unsigned short*)d_ws;                 // 8*S*256 B
    unsigned short* wsVT = wsK + (size_t)H * S * HD;              // 8*S*256 B

    const int nKblk = (H * S * 16) / 256;
    const int nVblk = H * (S >> 6);
    prepack<<<dim3(nKblk + nVblk), dim3(256), 0, stream>>>(k, v, wsK, wsVT, S);

    dim3 grid(H * (S / BR));   // 512 blocks
    dim3 block(256);
    fa_fwd<<<grid, block, 0, stream>>>(q, wsK, wsVT, cu, n_cu, out, S);
}